// Round 7
// baseline (166.444 us; speedup 1.0000x reference)
//
#include <hip/hip_runtime.h>
#include <hip/hip_bf16.h>
#include <stdint.h>

// EnergyAttention: out = -sum(logsumexp(SCALE * (Q K^T), axis=-1)) / SCALE
// Q = hs @ qp^T + qb (pre-scaled by SCALE*log2e), K = hs @ kp^T + kb, bf16.

typedef __bf16 bf16_t;
typedef bf16_t bf16x8 __attribute__((ext_vector_type(8)));
typedef float f32x4 __attribute__((ext_vector_type(4)));
typedef float f32x16 __attribute__((ext_vector_type(16)));

#define MFMA16(a,b,c) __builtin_amdgcn_mfma_f32_16x16x32_bf16(a,b,c,0,0,0)
#define MFMA32(a,b,c) __builtin_amdgcn_mfma_f32_32x32x16_bf16(a,b,c,0,0,0)
#define GLL16(g, l) __builtin_amdgcn_global_load_lds(                       \
    (const __attribute__((address_space(1))) void*)(g),                     \
    (__attribute__((address_space(3))) void*)(l), 16, 0, 0)

static constexpr int SEQ = 2048, BATCH = 2, EMBED = 1024, NH = 16, QKD = 64;
static constexpr int M_TOT = BATCH * SEQ;   // 4096
static constexpr int N_TOT = 2 * NH * QKD;  // 2048 (Q cols 0..1023, K cols 1024..2047)
static constexpr float C1 = 0.125f * 1.44269504088896340736f; // SCALE*log2(e)
static constexpr int NBLK_LSE = 1024;

// ---- single-launch f32 -> bf16 convert of hs, qp, kp ----
__global__ __launch_bounds__(256) void cvt_kernel(
    const float* __restrict__ hs, const float* __restrict__ qp,
    const float* __restrict__ kp, bf16_t* __restrict__ hsb,
    bf16_t* __restrict__ projb)
{
    int i = blockIdx.x * 256 + threadIdx.x;   // vec8 index, 786432 total
    const float* src; bf16_t* dst;
    if (i < 524288) { src = hs + (size_t)i * 8; dst = hsb + (size_t)i * 8; }
    else {
        int j = i - 524288;
        dst = projb + (size_t)j * 8;
        src = (j < 131072) ? qp + (size_t)j * 8 : kp + (size_t)(j - 131072) * 8;
    }
    f32x4 a = ((const f32x4*)src)[0], b = ((const f32x4*)src)[1];
    bf16x8 r;
    r[0]=(bf16_t)a[0]; r[1]=(bf16_t)a[1]; r[2]=(bf16_t)a[2]; r[3]=(bf16_t)a[3];
    r[4]=(bf16_t)b[0]; r[5]=(bf16_t)b[1]; r[6]=(bf16_t)b[2]; r[7]=(bf16_t)b[3];
    *(bf16x8*)dst = r;
}

// ---- Phase 1: C[m][n] = sum_d A[m][d]*B[n][d] + bias, bf16 out ----
// 128x128 tile, BK=64, double-buffered LDS, 1 barrier/K-step (round-3 verbatim).
__global__ __launch_bounds__(256) void proj_kernel(
    const bf16_t* __restrict__ A, const bf16_t* __restrict__ B,
    const float* __restrict__ qb, const float* __restrict__ kb,
    bf16_t* __restrict__ C)
{
    __shared__ __align__(16) char sA[2][16384];
    __shared__ __align__(16) char sB[2][16384];
    const int t = threadIdx.x, lane = t & 63, wv = t >> 6;
    const int bid = blockIdx.x;
    const int xcd = bid & 7, idx = bid >> 3;
    const int am0 = (xcd * 4 + (idx >> 4)) * 128;   // M-strip per XCD
    const int bn0 = (idx & 15) * 128;
    const int wr = wv >> 1, wc = wv & 1;
    const int l15 = lane & 15, g = lane >> 4;

    const int srow = wv * 8 + (lane >> 3);
    const int sgr  = (lane & 7) ^ ((lane >> 3) & 7);
    const bf16_t* ga = A + (size_t)(am0 + srow) * EMBED + 8 * sgr;
    const bf16_t* gb = B + (size_t)(bn0 + srow) * EMBED + 8 * sgr;
    const int lbase = wv * 1024;

    f32x4 acc[4][4] = {};

#pragma unroll
    for (int is = 0; is < 4; ++is) {
        GLL16(ga + (size_t)is * 32 * EMBED, &sA[0][lbase + is * 4096]);
        GLL16(gb + (size_t)is * 32 * EMBED, &sB[0][lbase + is * 4096]);
    }
    __syncthreads();

    int cur = 0;
    for (int kk = 0; kk < EMBED; kk += 64) {
        if (kk + 64 < EMBED) {
#pragma unroll
            for (int is = 0; is < 4; ++is) {
                GLL16(ga + kk + 64 + (size_t)is * 32 * EMBED, &sA[cur ^ 1][lbase + is * 4096]);
                GLL16(gb + kk + 64 + (size_t)is * 32 * EMBED, &sB[cur ^ 1][lbase + is * 4096]);
            }
        }
#pragma unroll
        for (int s = 0; s < 2; ++s) {
            bf16x8 af[4], bfv[4];
#pragma unroll
            for (int mt = 0; mt < 4; ++mt) {
                int row = wr * 64 + mt * 16 + l15;
                af[mt] = *(const bf16x8*)&sA[cur][row * 128 + 16 * (((s << 2) | g) ^ (row & 7))];
            }
#pragma unroll
            for (int nt = 0; nt < 4; ++nt) {
                int row = wc * 64 + nt * 16 + l15;
                bfv[nt] = *(const bf16x8*)&sB[cur][row * 128 + 16 * (((s << 2) | g) ^ (row & 7))];
            }
#pragma unroll
            for (int mt = 0; mt < 4; ++mt)
#pragma unroll
                for (int nt = 0; nt < 4; ++nt)
                    acc[mt][nt] = MFMA16(af[mt], bfv[nt], acc[mt][nt]);
        }
        __syncthreads();
        cur ^= 1;
    }

#pragma unroll
    for (int nt = 0; nt < 4; ++nt) {
        int col = bn0 + wc * 64 + nt * 16 + l15;
        float bias, scale;
        if (col < NH * QKD) { bias = qb[col & 63]; scale = C1; }   // Q: fold SCALE*log2e
        else                { bias = kb[col & 63]; scale = 1.0f; }
#pragma unroll
        for (int mt = 0; mt < 4; ++mt)
#pragma unroll
            for (int j = 0; j < 4; ++j) {
                int row = am0 + wr * 64 + mt * 16 + g * 4 + j;
                C[(size_t)row * N_TOT + col] = (bf16_t)((acc[mt][nt][j] + bias) * scale);
            }
    }
}

// ---- Phase 2: per (b,h): rowwise sum of exp2(Q K^T), + fused final reduce ----
// 1024 blocks x 64 Q-rows. Operand-swapped mfma32(K, Q): K-row (reduction) axis
// on registers -> in-register exp2 accumulation. K staged via global_load_lds in
// 128-row chunks, double-buffered (32KB LDS -> 4 blocks/CU), VGPR<=128 -> 16
// waves/CU. Wave wv covers chunk-local K rows [wv*32, wv*32+32).
__global__ __launch_bounds__(256, 4) void lse_kernel(
    const bf16_t* __restrict__ qk, float* __restrict__ red,
    unsigned* __restrict__ cnt, float* __restrict__ out)
{
    __shared__ __align__(16) char sK[2][16384];
    __shared__ float rows_s[4][64];
    __shared__ float wsf[4];
    __shared__ int lastflag;
    const int t = threadIdx.x, lane = t & 63, wv = t >> 6;
    const int bid = blockIdx.x;
    const int xcd = bid & 7, idx = bid >> 3;     // idx 0..127
    const int pair = xcd * 4 + (idx >> 5);       // 0..31, 4 pairs per XCD
    const int tile = idx & 31;                   // 0..31
    const int b = pair >> 4, h = pair & 15;
    const int qr0 = tile * 64;
    const int l31 = lane & 31, g5 = lane >> 5;
    const size_t base = (size_t)b * SEQ;
    const int KOFF = NH * QKD + h * QKD;

    // Q fragments (B-operand): lane holds Q-row qr0+mt*32+l31, k = kf*16+g5*8
    bf16x8 qf[2][4];
#pragma unroll
    for (int mt = 0; mt < 2; ++mt) {
        const bf16_t* qp_ = qk + (base + qr0 + mt * 32 + l31) * N_TOT + h * QKD + g5 * 8;
#pragma unroll
        for (int kf = 0; kf < 4; ++kf)
            qf[mt][kf] = *(const bf16x8*)(qp_ + kf * 16);
    }

    // K staging: instr l of wave wv covers chunk rows wv*32 + l*8 + (lane>>3),
    // granule lane&7; source granule pre-swizzled by row&7 = (lane>>3)&7.
    const int sgr = (lane & 7) ^ ((lane >> 3) & 7);
    const bf16_t* kbase = qk + (base + wv * 32 + (lane >> 3)) * N_TOT + KOFF + sgr * 8;

#define STAGE_K(BUF, KC) do {                                               \
    _Pragma("unroll") for (int l_ = 0; l_ < 4; ++l_)                        \
        GLL16(kbase + (size_t)((KC) + l_ * 8) * N_TOT,                      \
              &sK[BUF][(wv * 4 + l_) * 1024]); } while(0)

    float sume[2] = {0.f, 0.f};

    STAGE_K(0, 0);
    for (int c = 0; c < 16; ++c) {
        const int buf = c & 1;
        __syncthreads();                      // chunk c staged (drains vmcnt+lgkm)
        if (c < 15) STAGE_K(buf ^ 1, (c + 1) * 128);

        const int rl = wv * 32 + l31;         // chunk-local K-row
        bf16x8 kv[4];
#pragma unroll
        for (int kf = 0; kf < 4; ++kf)
            kv[kf] = *(const bf16x8*)&sK[buf][rl * 128 + 16 * ((kf * 2 + g5) ^ (rl & 7))];

        f32x16 sacc[2];
        __builtin_amdgcn_s_setprio(1);
#pragma unroll
        for (int mt = 0; mt < 2; ++mt) {
            f32x16 z = {};
            sacc[mt] = z;
#pragma unroll
            for (int kf = 0; kf < 4; ++kf)
                sacc[mt] = MFMA32(kv[kf], qf[mt][kf], sacc[mt]);
        }
        __builtin_amdgcn_s_setprio(0);
#pragma unroll
        for (int mt = 0; mt < 2; ++mt) {      // pairwise tree to cut add latency
            float e[8];
#pragma unroll
            for (int jj = 0; jj < 8; ++jj)
                e[jj] = __builtin_amdgcn_exp2f(sacc[mt][2 * jj])
                      + __builtin_amdgcn_exp2f(sacc[mt][2 * jj + 1]);
            e[0] += e[1]; e[2] += e[3]; e[4] += e[5]; e[6] += e[7];
            e[0] += e[2]; e[4] += e[6];
            sume[mt] += e[0] + e[4];
        }
    }
#undef STAGE_K

    // lane + g5-partner cover all 32 K-rows of each group for the same Q-row
    __syncthreads();
#pragma unroll
    for (int mt = 0; mt < 2; ++mt) {
        float v = sume[mt] + __shfl_xor(sume[mt], 32);
        if (g5 == 0) rows_s[wv][mt * 32 + l31] = v;
    }
    __syncthreads();

    float lg = 0.f;
    if (t < 64) {                             // wave 0: per-row log2 + reduce
        float tot = rows_s[0][t] + rows_s[1][t] + rows_s[2][t] + rows_s[3][t];
        lg = __builtin_amdgcn_logf(tot);      // v_log_f32 = log2
#pragma unroll
        for (int m = 1; m < 64; m <<= 1) lg += __shfl_xor(lg, m);
    }
    if (t == 0) {
        red[bid] = lg;
        __threadfence();
        unsigned d = atomicAdd(cnt, 1u);
        lastflag = (d == NBLK_LSE - 1);
    }
    __syncthreads();

    if (lastflag) {                           // last block: final reduce
        __threadfence();
        float s = red[t] + red[t + 256] + red[t + 512] + red[t + 768];
#pragma unroll
        for (int m = 1; m < 64; m <<= 1) s += __shfl_xor(s, m);
        if (lane == 0) wsf[wv] = s;
        __syncthreads();
        if (t == 0)
            out[0] = -8.0f * 0.69314718055994530942f * (wsf[0] + wsf[1] + wsf[2] + wsf[3]);
    }
}

extern "C" void kernel_launch(void* const* d_in, const int* in_sizes, int n_in,
                              void* d_out, int out_size, void* d_ws, size_t ws_size,
                              hipStream_t stream)
{
    const float* hs = (const float*)d_in[0];
    const float* qp = (const float*)d_in[1];
    const float* kp = (const float*)d_in[2];
    const float* qb = (const float*)d_in[3];
    const float* kb = (const float*)d_in[4];

    // ws layout: hsb (8MB) | projb (4MB) | qk (16MB) | red (4KB) | cnt (4B)
    bf16_t* hsb   = (bf16_t*)d_ws;
    bf16_t* projb = hsb + (size_t)M_TOT * EMBED;
    bf16_t* qkb   = projb + (size_t)N_TOT * EMBED;
    float*  red   = (float*)(qkb + (size_t)M_TOT * N_TOT);
    unsigned* cnt = (unsigned*)(red + NBLK_LSE);
    float*  out   = (float*)d_out;

    hipMemsetAsync(cnt, 0, sizeof(unsigned), stream);
    cvt_kernel<<<3072, 256, 0, stream>>>(hs, qp, kp, hsb, projb);
    proj_kernel<<<512, 256, 0, stream>>>(hsb, projb, qb, kb, qkb);
    lse_kernel<<<NBLK_LSE, 256, 0, stream>>>(qkb, red, cnt, out);
}

// Round 8
// 96.864 us; speedup vs baseline: 1.7183x; 1.7183x over previous
//
#include <hip/hip_runtime.h>
#include <hip/hip_bf16.h>
#include <stdint.h>

// EnergyAttention: out = -sum(logsumexp(SCALE * (Q K^T), axis=-1)) / SCALE
// Q = hs @ qp^T + qb (pre-scaled by SCALE*log2e), K = hs @ kp^T + kb, bf16.

typedef __bf16 bf16_t;
typedef bf16_t bf16x8 __attribute__((ext_vector_type(8)));
typedef float f32x4 __attribute__((ext_vector_type(4)));
typedef float f32x16 __attribute__((ext_vector_type(16)));

#define MFMA16(a,b,c) __builtin_amdgcn_mfma_f32_16x16x32_bf16(a,b,c,0,0,0)
#define MFMA32(a,b,c) __builtin_amdgcn_mfma_f32_32x32x16_bf16(a,b,c,0,0,0)
#define GLL16(g, l) __builtin_amdgcn_global_load_lds(                       \
    (const __attribute__((address_space(1))) void*)(g),                     \
    (__attribute__((address_space(3))) void*)(l), 16, 0, 0)

static constexpr int SEQ = 2048, BATCH = 2, EMBED = 1024, NH = 16, QKD = 64;
static constexpr int M_TOT = BATCH * SEQ;   // 4096
static constexpr int N_TOT = 2 * NH * QKD;  // 2048 (Q cols 0..1023, K cols 1024..2047)
static constexpr float C1 = 0.125f * 1.44269504088896340736f; // SCALE*log2(e)
static constexpr int NBLK_LSE = 1024;

// ---- single-launch f32 -> bf16 convert of hs, qp, kp ----
__global__ __launch_bounds__(256) void cvt_kernel(
    const float* __restrict__ hs, const float* __restrict__ qp,
    const float* __restrict__ kp, bf16_t* __restrict__ hsb,
    bf16_t* __restrict__ projb)
{
    int i = blockIdx.x * 256 + threadIdx.x;   // vec8 index, 786432 total
    const float* src; bf16_t* dst;
    if (i < 524288) { src = hs + (size_t)i * 8; dst = hsb + (size_t)i * 8; }
    else {
        int j = i - 524288;
        dst = projb + (size_t)j * 8;
        src = (j < 131072) ? qp + (size_t)j * 8 : kp + (size_t)(j - 131072) * 8;
    }
    f32x4 a = ((const f32x4*)src)[0], b = ((const f32x4*)src)[1];
    bf16x8 r;
    r[0]=(bf16_t)a[0]; r[1]=(bf16_t)a[1]; r[2]=(bf16_t)a[2]; r[3]=(bf16_t)a[3];
    r[4]=(bf16_t)b[0]; r[5]=(bf16_t)b[1]; r[6]=(bf16_t)b[2]; r[7]=(bf16_t)b[3];
    *(bf16x8*)dst = r;
}

// ---- Phase 1: C[m][n] = sum_d A[m][d]*B[n][d] + bias, bf16 out ----
// 128x128 tile, BK=64, double-buffered LDS, 1 barrier/K-step (round-3 verbatim).
__global__ __launch_bounds__(256) void proj_kernel(
    const bf16_t* __restrict__ A, const bf16_t* __restrict__ B,
    const float* __restrict__ qb, const float* __restrict__ kb,
    bf16_t* __restrict__ C)
{
    __shared__ __align__(16) char sA[2][16384];
    __shared__ __align__(16) char sB[2][16384];
    const int t = threadIdx.x, lane = t & 63, wv = t >> 6;
    const int bid = blockIdx.x;
    const int xcd = bid & 7, idx = bid >> 3;
    const int am0 = (xcd * 4 + (idx >> 4)) * 128;   // M-strip per XCD
    const int bn0 = (idx & 15) * 128;
    const int wr = wv >> 1, wc = wv & 1;
    const int l15 = lane & 15, g = lane >> 4;

    const int srow = wv * 8 + (lane >> 3);
    const int sgr  = (lane & 7) ^ ((lane >> 3) & 7);
    const bf16_t* ga = A + (size_t)(am0 + srow) * EMBED + 8 * sgr;
    const bf16_t* gb = B + (size_t)(bn0 + srow) * EMBED + 8 * sgr;
    const int lbase = wv * 1024;

    f32x4 acc[4][4] = {};

#pragma unroll
    for (int is = 0; is < 4; ++is) {
        GLL16(ga + (size_t)is * 32 * EMBED, &sA[0][lbase + is * 4096]);
        GLL16(gb + (size_t)is * 32 * EMBED, &sB[0][lbase + is * 4096]);
    }
    __syncthreads();

    int cur = 0;
    for (int kk = 0; kk < EMBED; kk += 64) {
        if (kk + 64 < EMBED) {
#pragma unroll
            for (int is = 0; is < 4; ++is) {
                GLL16(ga + kk + 64 + (size_t)is * 32 * EMBED, &sA[cur ^ 1][lbase + is * 4096]);
                GLL16(gb + kk + 64 + (size_t)is * 32 * EMBED, &sB[cur ^ 1][lbase + is * 4096]);
            }
        }
#pragma unroll
        for (int s = 0; s < 2; ++s) {
            bf16x8 af[4], bfv[4];
#pragma unroll
            for (int mt = 0; mt < 4; ++mt) {
                int row = wr * 64 + mt * 16 + l15;
                af[mt] = *(const bf16x8*)&sA[cur][row * 128 + 16 * (((s << 2) | g) ^ (row & 7))];
            }
#pragma unroll
            for (int nt = 0; nt < 4; ++nt) {
                int row = wc * 64 + nt * 16 + l15;
                bfv[nt] = *(const bf16x8*)&sB[cur][row * 128 + 16 * (((s << 2) | g) ^ (row & 7))];
            }
#pragma unroll
            for (int mt = 0; mt < 4; ++mt)
#pragma unroll
                for (int nt = 0; nt < 4; ++nt)
                    acc[mt][nt] = MFMA16(af[mt], bfv[nt], acc[mt][nt]);
        }
        __syncthreads();
        cur ^= 1;
    }

#pragma unroll
    for (int nt = 0; nt < 4; ++nt) {
        int col = bn0 + wc * 64 + nt * 16 + l15;
        float bias, scale;
        if (col < NH * QKD) { bias = qb[col & 63]; scale = C1; }   // Q: fold SCALE*log2e
        else                { bias = kb[col & 63]; scale = 1.0f; }
#pragma unroll
        for (int mt = 0; mt < 4; ++mt)
#pragma unroll
            for (int j = 0; j < 4; ++j) {
                int row = am0 + wr * 64 + mt * 16 + g * 4 + j;
                C[(size_t)row * N_TOT + col] = (bf16_t)((acc[mt][nt][j] + bias) * scale);
            }
    }
}

// ---- Phase 2: per (b,h): rowwise sum of exp2(Q K^T), + fused final reduce ----
// 1024 blocks x 64 Q-rows; wave wv covers K rows [wv*512, wv*512+512).
// Operand-swapped mfma32(K, Q): K-row (reduction) axis lands on registers ->
// in-register exp2 accumulation. DIRECT global K loads (L2-resident panel; no
// LDS staging, no main-loop barriers), kn prefetch one ct ahead.
__global__ __launch_bounds__(256) void lse_kernel(
    const bf16_t* __restrict__ qk, float* __restrict__ red,
    unsigned* __restrict__ cnt, float* __restrict__ out)
{
    __shared__ float rows_s[4][64];
    __shared__ float wsf[4];
    __shared__ int lastflag;
    const int t = threadIdx.x, lane = t & 63, wv = t >> 6;
    const int bid = blockIdx.x;
    const int xcd = bid & 7, idx = bid >> 3;     // idx 0..127
    const int pair = xcd * 4 + (idx >> 5);       // 0..31, 4 pairs per XCD
    const int tile = idx & 31;                   // 0..31
    const int b = pair >> 4, h = pair & 15;
    const int qr0 = tile * 64;
    const int l31 = lane & 31, g5 = lane >> 5;
    const size_t base = (size_t)b * SEQ;

    // Q fragments (B-operand): lane holds Q-row qr0+mt*32+l31, k = kf*16+g5*8
    bf16x8 qf[2][4];
#pragma unroll
    for (int mt = 0; mt < 2; ++mt) {
        const bf16_t* qp_ = qk + (base + qr0 + mt * 32 + l31) * N_TOT + h * QKD + g5 * 8;
#pragma unroll
        for (int kf = 0; kf < 4; ++kf)
            qf[mt][kf] = *(const bf16x8*)(qp_ + kf * 16);
    }

    // K fragment base (A-operand): lane holds K-row (wv*512 + ct*32 + l31)
    const bf16_t* kb_ = qk + (base + wv * 512 + l31) * N_TOT + NH * QKD + h * QKD + g5 * 8;

    float sume[2] = {0.f, 0.f};

    bf16x8 kv[4];
#pragma unroll
    for (int kf = 0; kf < 4; ++kf) kv[kf] = *(const bf16x8*)(kb_ + kf * 16);

    for (int ct = 0; ct < 16; ++ct) {
        // prefetch next K-frag set (clamped on last iter)
        bf16x8 kn[4];
        const bf16_t* kn_p = kb_ + (size_t)((ct < 15 ? ct + 1 : 15) * 32) * N_TOT;
#pragma unroll
        for (int kf = 0; kf < 4; ++kf) kn[kf] = *(const bf16x8*)(kn_p + kf * 16);

        f32x16 sacc[2];
        __builtin_amdgcn_s_setprio(1);
#pragma unroll
        for (int mt = 0; mt < 2; ++mt) {
            f32x16 z = {};
            sacc[mt] = z;
#pragma unroll
            for (int kf = 0; kf < 4; ++kf)
                sacc[mt] = MFMA32(kv[kf], qf[mt][kf], sacc[mt]);
        }
        __builtin_amdgcn_s_setprio(0);
#pragma unroll
        for (int mt = 0; mt < 2; ++mt) {      // pairwise tree to cut add latency
            float e[8];
#pragma unroll
            for (int jj = 0; jj < 8; ++jj)
                e[jj] = __builtin_amdgcn_exp2f(sacc[mt][2 * jj])
                      + __builtin_amdgcn_exp2f(sacc[mt][2 * jj + 1]);
            e[0] += e[1]; e[2] += e[3]; e[4] += e[5]; e[6] += e[7];
            e[0] += e[2]; e[4] += e[6];
            sume[mt] += e[0] + e[4];
        }
#pragma unroll
        for (int kf = 0; kf < 4; ++kf) kv[kf] = kn[kf];
    }

    // lane + g5-partner cover all 32 K-rows of each ct for the same Q-row
#pragma unroll
    for (int mt = 0; mt < 2; ++mt) {
        float v = sume[mt] + __shfl_xor(sume[mt], 32);
        if (g5 == 0) rows_s[wv][mt * 32 + l31] = v;
    }
    __syncthreads();

    float lg = 0.f;
    if (t < 64) {                             // wave 0: per-row log2 + reduce
        float tot = rows_s[0][t] + rows_s[1][t] + rows_s[2][t] + rows_s[3][t];
        lg = __builtin_amdgcn_logf(tot);      // v_log_f32 = log2
#pragma unroll
        for (int m = 1; m < 64; m <<= 1) lg += __shfl_xor(lg, m);
    }
    if (t == 0) {
        red[bid] = lg;
        __threadfence();
        unsigned d = atomicAdd(cnt, 1u);
        lastflag = (d == NBLK_LSE - 1);
    }
    __syncthreads();

    if (lastflag) {                           // last block: final reduce
        __threadfence();
        float s = red[t] + red[t + 256] + red[t + 512] + red[t + 768];
#pragma unroll
        for (int m = 1; m < 64; m <<= 1) s += __shfl_xor(s, m);
        if (lane == 0) wsf[wv] = s;
        __syncthreads();
        if (t == 0)
            out[0] = -8.0f * 0.69314718055994530942f * (wsf[0] + wsf[1] + wsf[2] + wsf[3]);
    }
}

extern "C" void kernel_launch(void* const* d_in, const int* in_sizes, int n_in,
                              void* d_out, int out_size, void* d_ws, size_t ws_size,
                              hipStream_t stream)
{
    const float* hs = (const float*)d_in[0];
    const float* qp = (const float*)d_in[1];
    const float* kp = (const float*)d_in[2];
    const float* qb = (const float*)d_in[3];
    const float* kb = (const float*)d_in[4];

    // ws layout: hsb (8MB) | projb (4MB) | qk (16MB) | red (4KB) | cnt (4B)
    bf16_t* hsb   = (bf16_t*)d_ws;
    bf16_t* projb = hsb + (size_t)M_TOT * EMBED;
    bf16_t* qkb   = projb + (size_t)N_TOT * EMBED;
    float*  red   = (float*)(qkb + (size_t)M_TOT * N_TOT);
    unsigned* cnt = (unsigned*)(red + NBLK_LSE);
    float*  out   = (float*)d_out;

    hipMemsetAsync(cnt, 0, sizeof(unsigned), stream);
    cvt_kernel<<<3072, 256, 0, stream>>>(hs, qp, kp, hsb, projb);
    proj_kernel<<<512, 256, 0, stream>>>(hsb, projb, qb, kb, qkb);
    lse_kernel<<<NBLK_LSE, 256, 0, stream>>>(qkb, red, cnt, out);
}

// Round 10
// 87.691 us; speedup vs baseline: 1.8981x; 1.1046x over previous
//
#include <hip/hip_runtime.h>
#include <hip/hip_bf16.h>
#include <stdint.h>

// EnergyAttention: out = -sum(logsumexp(SCALE * (Q K^T), axis=-1)) / SCALE
// Q = hs @ qp^T + qb (pre-scaled by SCALE*log2e), K = hs @ kp^T + kb, bf16.

typedef __bf16 bf16_t;
typedef bf16_t bf16x8 __attribute__((ext_vector_type(8)));
typedef float f32x4 __attribute__((ext_vector_type(4)));
typedef float f32x16 __attribute__((ext_vector_type(16)));

#define MFMA16(a,b,c) __builtin_amdgcn_mfma_f32_16x16x32_bf16(a,b,c,0,0,0)
#define MFMA32(a,b,c) __builtin_amdgcn_mfma_f32_32x32x16_bf16(a,b,c,0,0,0)
#define GLL16(g, l) __builtin_amdgcn_global_load_lds(                       \
    (const __attribute__((address_space(1))) void*)(g),                     \
    (__attribute__((address_space(3))) void*)(l), 16, 0, 0)

static constexpr int SEQ = 2048, BATCH = 2, EMBED = 1024, NH = 16, QKD = 64;
static constexpr int M_TOT = BATCH * SEQ;   // 4096
static constexpr int N_TOT = 2 * NH * QKD;  // 2048 (Q cols 0..1023, K cols 1024..2047)
static constexpr float C1 = 0.125f * 1.44269504088896340736f; // SCALE*log2(e)
static constexpr int NBLK_LSE = 1024;

// ---- single-launch f32 -> bf16 convert of hs, qp, kp ----
__global__ __launch_bounds__(256) void cvt_kernel(
    const float* __restrict__ hs, const float* __restrict__ qp,
    const float* __restrict__ kp, bf16_t* __restrict__ hsb,
    bf16_t* __restrict__ projb)
{
    int i = blockIdx.x * 256 + threadIdx.x;   // vec8 index, 786432 total
    const float* src; bf16_t* dst;
    if (i < 524288) { src = hs + (size_t)i * 8; dst = hsb + (size_t)i * 8; }
    else {
        int j = i - 524288;
        dst = projb + (size_t)j * 8;
        src = (j < 131072) ? qp + (size_t)j * 8 : kp + (size_t)(j - 131072) * 8;
    }
    f32x4 a = ((const f32x4*)src)[0], b = ((const f32x4*)src)[1];
    bf16x8 r;
    r[0]=(bf16_t)a[0]; r[1]=(bf16_t)a[1]; r[2]=(bf16_t)a[2]; r[3]=(bf16_t)a[3];
    r[4]=(bf16_t)b[0]; r[5]=(bf16_t)b[1]; r[6]=(bf16_t)b[2]; r[7]=(bf16_t)b[3];
    *(bf16x8*)dst = r;
}

// ---- Phase 1: C[m][n] = sum_d A[m][d]*B[n][d] + bias, bf16 out ----
// 128x128 tile, BK=64, double-buffered LDS, 1 barrier/K-step (round-3 verbatim).
__global__ __launch_bounds__(256) void proj_kernel(
    const bf16_t* __restrict__ A, const bf16_t* __restrict__ B,
    const float* __restrict__ qb, const float* __restrict__ kb,
    bf16_t* __restrict__ C)
{
    __shared__ __align__(16) char sA[2][16384];
    __shared__ __align__(16) char sB[2][16384];
    const int t = threadIdx.x, lane = t & 63, wv = t >> 6;
    const int bid = blockIdx.x;
    const int xcd = bid & 7, idx = bid >> 3;
    const int am0 = (xcd * 4 + (idx >> 4)) * 128;   // M-strip per XCD
    const int bn0 = (idx & 15) * 128;
    const int wr = wv >> 1, wc = wv & 1;
    const int l15 = lane & 15, g = lane >> 4;

    const int srow = wv * 8 + (lane >> 3);
    const int sgr  = (lane & 7) ^ ((lane >> 3) & 7);
    const bf16_t* ga = A + (size_t)(am0 + srow) * EMBED + 8 * sgr;
    const bf16_t* gb = B + (size_t)(bn0 + srow) * EMBED + 8 * sgr;
    const int lbase = wv * 1024;

    f32x4 acc[4][4] = {};

#pragma unroll
    for (int is = 0; is < 4; ++is) {
        GLL16(ga + (size_t)is * 32 * EMBED, &sA[0][lbase + is * 4096]);
        GLL16(gb + (size_t)is * 32 * EMBED, &sB[0][lbase + is * 4096]);
    }
    __syncthreads();

    int cur = 0;
    for (int kk = 0; kk < EMBED; kk += 64) {
        if (kk + 64 < EMBED) {
#pragma unroll
            for (int is = 0; is < 4; ++is) {
                GLL16(ga + kk + 64 + (size_t)is * 32 * EMBED, &sA[cur ^ 1][lbase + is * 4096]);
                GLL16(gb + kk + 64 + (size_t)is * 32 * EMBED, &sB[cur ^ 1][lbase + is * 4096]);
            }
        }
#pragma unroll
        for (int s = 0; s < 2; ++s) {
            bf16x8 af[4], bfv[4];
#pragma unroll
            for (int mt = 0; mt < 4; ++mt) {
                int row = wr * 64 + mt * 16 + l15;
                af[mt] = *(const bf16x8*)&sA[cur][row * 128 + 16 * (((s << 2) | g) ^ (row & 7))];
            }
#pragma unroll
            for (int nt = 0; nt < 4; ++nt) {
                int row = wc * 64 + nt * 16 + l15;
                bfv[nt] = *(const bf16x8*)&sB[cur][row * 128 + 16 * (((s << 2) | g) ^ (row & 7))];
            }
#pragma unroll
            for (int mt = 0; mt < 4; ++mt)
#pragma unroll
                for (int nt = 0; nt < 4; ++nt)
                    acc[mt][nt] = MFMA16(af[mt], bfv[nt], acc[mt][nt]);
        }
        __syncthreads();
        cur ^= 1;
    }

#pragma unroll
    for (int nt = 0; nt < 4; ++nt) {
        int col = bn0 + wc * 64 + nt * 16 + l15;
        float bias, scale;
        if (col < NH * QKD) { bias = qb[col & 63]; scale = C1; }   // Q: fold SCALE*log2e
        else                { bias = kb[col & 63]; scale = 1.0f; }
#pragma unroll
        for (int mt = 0; mt < 4; ++mt)
#pragma unroll
            for (int j = 0; j < 4; ++j) {
                int row = am0 + wr * 64 + mt * 16 + g * 4 + j;
                C[(size_t)row * N_TOT + col] = (bf16_t)((acc[mt][nt][j] + bias) * scale);
            }
    }
}

// ---- Phase 1.5: repack K into MFMA-fragment-major layout ----
// kfrag[((pair*64 + ct)*4 + kf)*512 + lane*8] (bf16 units) = 8 consecutive
// k-elems (k = kf*16 + (lane>>5)*8) of K-row (ct*32 + (lane&31)) of pair.
// Gather-read once (amortizes the 4KB-stride gather), coalesced 1KB writes.
__global__ __launch_bounds__(256) void repack_kernel(
    const bf16_t* __restrict__ qk, bf16_t* __restrict__ kfrag)
{
    const int t = threadIdx.x, lane = t & 63, wv = t >> 6;
    const int bid = blockIdx.x;                  // 512 blocks
    const int pair = bid >> 4;                   // 0..31
    const int ct   = (bid & 15) * 4 + wv;        // 0..63
    const int b = pair >> 4, h = pair & 15;
    const int l31 = lane & 31, g5 = lane >> 5;

    const bf16_t* src = qk + ((size_t)b * SEQ + ct * 32 + l31) * N_TOT
                           + NH * QKD + h * QKD + g5 * 8;
    bf16_t* dst = kfrag + ((size_t)(pair * 64 + ct) * 4) * 512 + lane * 8;

#pragma unroll
    for (int kf = 0; kf < 4; ++kf)
        *(bf16x8*)(dst + kf * 512) = *(const bf16x8*)(src + kf * 16);
}

// ---- Phase 2: per (b,h): rowwise sum of exp2(Q K^T), + fused final reduce ----
// 1024 blocks x 64 Q-rows; wave wv covers frag-cts [wv*16, wv*16+16).
// Operand-swapped mfma32(K, Q): K-row (reduction) axis lands on registers ->
// in-register exp2 accumulation. K loads are fully-coalesced 1KB bursts from
// the fragged buffer (L2-resident). No LDS staging, no main-loop barriers.
__global__ __launch_bounds__(256) void lse_kernel(
    const bf16_t* __restrict__ qk, const bf16_t* __restrict__ kfrag,
    float* __restrict__ red, unsigned* __restrict__ cnt, float* __restrict__ out)
{
    __shared__ float rows_s[4][64];
    __shared__ float wsf[4];
    __shared__ int lastflag;
    const int t = threadIdx.x, lane = t & 63, wv = t >> 6;
    const int bid = blockIdx.x;
    const int xcd = bid & 7, idx = bid >> 3;     // idx 0..127
    const int pair = xcd * 4 + (idx >> 5);       // 0..31, 4 pairs per XCD
    const int tile = idx & 31;                   // 0..31
    const int b = pair >> 4, h = pair & 15;
    const int qr0 = tile * 64;
    const int l31 = lane & 31, g5 = lane >> 5;
    const size_t base = (size_t)b * SEQ;

    // Q fragments (B-operand): lane holds Q-row qr0+mt*32+l31, k = kf*16+g5*8
    bf16x8 qf[2][4];
#pragma unroll
    for (int mt = 0; mt < 2; ++mt) {
        const bf16_t* qp_ = qk + (base + qr0 + mt * 32 + l31) * N_TOT + h * QKD + g5 * 8;
#pragma unroll
        for (int kf = 0; kf < 4; ++kf)
            qf[mt][kf] = *(const bf16x8*)(qp_ + kf * 16);
    }

    // K fragments: coalesced from fragged buffer; wave wv owns cts wv*16..wv*16+15
    const bf16_t* kfb = kfrag + ((size_t)(pair * 64 + wv * 16) * 4) * 512 + lane * 8;

    float sume[2] = {0.f, 0.f};

    bf16x8 kv[4];
#pragma unroll
    for (int kf = 0; kf < 4; ++kf) kv[kf] = *(const bf16x8*)(kfb + kf * 512);

    for (int ct = 0; ct < 16; ++ct) {
        // prefetch next ct's K-frags (clamped on last iter)
        bf16x8 kn[4];
        const bf16_t* kn_p = kfb + (size_t)(ct < 15 ? ct + 1 : 15) * 2048;
#pragma unroll
        for (int kf = 0; kf < 4; ++kf) kn[kf] = *(const bf16x8*)(kn_p + kf * 512);

        f32x16 sacc[2];
        __builtin_amdgcn_s_setprio(1);
#pragma unroll
        for (int mt = 0; mt < 2; ++mt) {
            f32x16 z = {};
            sacc[mt] = z;
#pragma unroll
            for (int kf = 0; kf < 4; ++kf)
                sacc[mt] = MFMA32(kv[kf], qf[mt][kf], sacc[mt]);
        }
        __builtin_amdgcn_s_setprio(0);
#pragma unroll
        for (int mt = 0; mt < 2; ++mt) {      // pairwise tree to cut add latency
            float e[8];
#pragma unroll
            for (int jj = 0; jj < 8; ++jj)
                e[jj] = __builtin_amdgcn_exp2f(sacc[mt][2 * jj])
                      + __builtin_amdgcn_exp2f(sacc[mt][2 * jj + 1]);
            e[0] += e[1]; e[2] += e[3]; e[4] += e[5]; e[6] += e[7];
            e[0] += e[2]; e[4] += e[6];
            sume[mt] += e[0] + e[4];
        }
#pragma unroll
        for (int kf = 0; kf < 4; ++kf) kv[kf] = kn[kf];
    }

    // lane + g5-partner cover all 32 K-rows of each ct for the same Q-row
#pragma unroll
    for (int mt = 0; mt < 2; ++mt) {
        float v = sume[mt] + __shfl_xor(sume[mt], 32);
        if (g5 == 0) rows_s[wv][mt * 32 + l31] = v;
    }
    __syncthreads();

    float lg = 0.f;
    if (t < 64) {                             // wave 0: per-row log2 + reduce
        float tot = rows_s[0][t] + rows_s[1][t] + rows_s[2][t] + rows_s[3][t];
        lg = __builtin_amdgcn_logf(tot);      // v_log_f32 = log2
#pragma unroll
        for (int m = 1; m < 64; m <<= 1) lg += __shfl_xor(lg, m);
    }
    if (t == 0) {
        red[bid] = lg;
        __threadfence();
        unsigned d = atomicAdd(cnt, 1u);
        lastflag = (d == NBLK_LSE - 1);
    }
    __syncthreads();

    if (lastflag) {                           // last block: final reduce
        __threadfence();
        float s = red[t] + red[t + 256] + red[t + 512] + red[t + 768];
#pragma unroll
        for (int m = 1; m < 64; m <<= 1) s += __shfl_xor(s, m);
        if (lane == 0) wsf[wv] = s;
        __syncthreads();
        if (t == 0)
            out[0] = -8.0f * 0.69314718055994530942f * (wsf[0] + wsf[1] + wsf[2] + wsf[3]);
    }
}

extern "C" void kernel_launch(void* const* d_in, const int* in_sizes, int n_in,
                              void* d_out, int out_size, void* d_ws, size_t ws_size,
                              hipStream_t stream)
{
    const float* hs = (const float*)d_in[0];
    const float* qp = (const float*)d_in[1];
    const float* kp = (const float*)d_in[2];
    const float* qb = (const float*)d_in[3];
    const float* kb = (const float*)d_in[4];

    // ws layout: hsb (8MB, reused as kfrag after proj) | projb (4MB) | qk (16MB)
    //            | red (4KB) | cnt (4B)
    bf16_t* hsb   = (bf16_t*)d_ws;
    bf16_t* projb = hsb + (size_t)M_TOT * EMBED;
    bf16_t* qkb   = projb + (size_t)N_TOT * EMBED;
    float*  red   = (float*)(qkb + (size_t)M_TOT * N_TOT);
    unsigned* cnt = (unsigned*)(red + NBLK_LSE);
    float*  out   = (float*)d_out;
    bf16_t* kfrag = hsb;   // hsb is dead after proj; 8MB = exactly kfrag size

    hipMemsetAsync(cnt, 0, sizeof(unsigned), stream);
    cvt_kernel<<<3072, 256, 0, stream>>>(hs, qp, kp, hsb, projb);
    proj_kernel<<<512, 256, 0, stream>>>(hsb, projb, qb, kb, qkb);
    repack_kernel<<<512, 256, 0, stream>>>(qkb, kfrag);
    lse_kernel<<<NBLK_LSE, 256, 0, stream>>>(qkb, kfrag, red, cnt, out);
}

// Round 11
// 77.284 us; speedup vs baseline: 2.1537x; 1.1347x over previous
//
#include <hip/hip_runtime.h>
#include <hip/hip_bf16.h>
#include <stdint.h>

// EnergyAttention: out = -sum(logsumexp(SCALE * (Q K^T), axis=-1)) / SCALE
// Q = hs @ qp^T + qb (pre-scaled by SCALE*log2e), K = hs @ kp^T + kb, bf16.

typedef __bf16 bf16_t;
typedef bf16_t bf16x8 __attribute__((ext_vector_type(8)));
typedef float f32x4 __attribute__((ext_vector_type(4)));
typedef float f32x16 __attribute__((ext_vector_type(16)));

#define MFMA16(a,b,c) __builtin_amdgcn_mfma_f32_16x16x32_bf16(a,b,c,0,0,0)
#define MFMA32(a,b,c) __builtin_amdgcn_mfma_f32_32x32x16_bf16(a,b,c,0,0,0)
#define GLL16(g, l) __builtin_amdgcn_global_load_lds(                       \
    (const __attribute__((address_space(1))) void*)(g),                     \
    (__attribute__((address_space(3))) void*)(l), 16, 0, 0)

static constexpr int SEQ = 2048, BATCH = 2, EMBED = 1024, NH = 16, QKD = 64;
static constexpr int M_TOT = BATCH * SEQ;   // 4096
static constexpr int N_TOT = 2 * NH * QKD;  // 2048 (Q cols 0..1023, K cols 1024..2047)
static constexpr float C1 = 0.125f * 1.44269504088896340736f; // SCALE*log2(e)
static constexpr int NBLK_LSE = 512;

// ---- single-launch f32 -> bf16 convert of hs, qp, kp ----
__global__ __launch_bounds__(256) void cvt_kernel(
    const float* __restrict__ hs, const float* __restrict__ qp,
    const float* __restrict__ kp, bf16_t* __restrict__ hsb,
    bf16_t* __restrict__ projb)
{
    int i = blockIdx.x * 256 + threadIdx.x;   // vec8 index, 786432 total
    const float* src; bf16_t* dst;
    if (i < 524288) { src = hs + (size_t)i * 8; dst = hsb + (size_t)i * 8; }
    else {
        int j = i - 524288;
        dst = projb + (size_t)j * 8;
        src = (j < 131072) ? qp + (size_t)j * 8 : kp + (size_t)(j - 131072) * 8;
    }
    f32x4 a = ((const f32x4*)src)[0], b = ((const f32x4*)src)[1];
    bf16x8 r;
    r[0]=(bf16_t)a[0]; r[1]=(bf16_t)a[1]; r[2]=(bf16_t)a[2]; r[3]=(bf16_t)a[3];
    r[4]=(bf16_t)b[0]; r[5]=(bf16_t)b[1]; r[6]=(bf16_t)b[2]; r[7]=(bf16_t)b[3];
    *(bf16x8*)dst = r;
}

// ---- Phase 1: C[m][n] = sum_d A[m][d]*B[n][d] + bias, bf16 out ----
// 128x128 tile, BK=64, double-buffered LDS, 1 barrier/K-step (round-3 verbatim).
__global__ __launch_bounds__(256) void proj_kernel(
    const bf16_t* __restrict__ A, const bf16_t* __restrict__ B,
    const float* __restrict__ qb, const float* __restrict__ kb,
    bf16_t* __restrict__ C)
{
    __shared__ __align__(16) char sA[2][16384];
    __shared__ __align__(16) char sB[2][16384];
    const int t = threadIdx.x, lane = t & 63, wv = t >> 6;
    const int bid = blockIdx.x;
    const int xcd = bid & 7, idx = bid >> 3;
    const int am0 = (xcd * 4 + (idx >> 4)) * 128;   // M-strip per XCD
    const int bn0 = (idx & 15) * 128;
    const int wr = wv >> 1, wc = wv & 1;
    const int l15 = lane & 15, g = lane >> 4;

    const int srow = wv * 8 + (lane >> 3);
    const int sgr  = (lane & 7) ^ ((lane >> 3) & 7);
    const bf16_t* ga = A + (size_t)(am0 + srow) * EMBED + 8 * sgr;
    const bf16_t* gb = B + (size_t)(bn0 + srow) * EMBED + 8 * sgr;
    const int lbase = wv * 1024;

    f32x4 acc[4][4] = {};

#pragma unroll
    for (int is = 0; is < 4; ++is) {
        GLL16(ga + (size_t)is * 32 * EMBED, &sA[0][lbase + is * 4096]);
        GLL16(gb + (size_t)is * 32 * EMBED, &sB[0][lbase + is * 4096]);
    }
    __syncthreads();

    int cur = 0;
    for (int kk = 0; kk < EMBED; kk += 64) {
        if (kk + 64 < EMBED) {
#pragma unroll
            for (int is = 0; is < 4; ++is) {
                GLL16(ga + kk + 64 + (size_t)is * 32 * EMBED, &sA[cur ^ 1][lbase + is * 4096]);
                GLL16(gb + kk + 64 + (size_t)is * 32 * EMBED, &sB[cur ^ 1][lbase + is * 4096]);
            }
        }
#pragma unroll
        for (int s = 0; s < 2; ++s) {
            bf16x8 af[4], bfv[4];
#pragma unroll
            for (int mt = 0; mt < 4; ++mt) {
                int row = wr * 64 + mt * 16 + l15;
                af[mt] = *(const bf16x8*)&sA[cur][row * 128 + 16 * (((s << 2) | g) ^ (row & 7))];
            }
#pragma unroll
            for (int nt = 0; nt < 4; ++nt) {
                int row = wc * 64 + nt * 16 + l15;
                bfv[nt] = *(const bf16x8*)&sB[cur][row * 128 + 16 * (((s << 2) | g) ^ (row & 7))];
            }
#pragma unroll
            for (int mt = 0; mt < 4; ++mt)
#pragma unroll
                for (int nt = 0; nt < 4; ++nt)
                    acc[mt][nt] = MFMA16(af[mt], bfv[nt], acc[mt][nt]);
        }
        __syncthreads();
        cur ^= 1;
    }

#pragma unroll
    for (int nt = 0; nt < 4; ++nt) {
        int col = bn0 + wc * 64 + nt * 16 + l15;
        float bias, scale;
        if (col < NH * QKD) { bias = qb[col & 63]; scale = C1; }   // Q: fold SCALE*log2e
        else                { bias = kb[col & 63]; scale = 1.0f; }
#pragma unroll
        for (int mt = 0; mt < 4; ++mt)
#pragma unroll
            for (int j = 0; j < 4; ++j) {
                int row = am0 + wr * 64 + mt * 16 + g * 4 + j;
                C[(size_t)row * N_TOT + col] = (bf16_t)((acc[mt][nt][j] + bias) * scale);
            }
    }
}

// ---- Phase 1.5: repack K into MFMA-fragment-major layout ----
// kfrag[((pair*64 + ct)*4 + kf)*512 + lane*8] (bf16 units) = 8 consecutive
// k-elems (k = kf*16 + (lane>>5)*8) of K-row (ct*32 + (lane&31)) of pair.
__global__ __launch_bounds__(256) void repack_kernel(
    const bf16_t* __restrict__ qk, bf16_t* __restrict__ kfrag)
{
    const int t = threadIdx.x, lane = t & 63, wv = t >> 6;
    const int bid = blockIdx.x;                  // 512 blocks
    const int pair = bid >> 4;                   // 0..31
    const int ct   = (bid & 15) * 4 + wv;        // 0..63
    const int b = pair >> 4, h = pair & 15;
    const int l31 = lane & 31, g5 = lane >> 5;

    const bf16_t* src = qk + ((size_t)b * SEQ + ct * 32 + l31) * N_TOT
                           + NH * QKD + h * QKD + g5 * 8;
    bf16_t* dst = kfrag + ((size_t)(pair * 64 + ct) * 4) * 512 + lane * 8;

#pragma unroll
    for (int kf = 0; kf < 4; ++kf)
        *(bf16x8*)(dst + kf * 512) = *(const bf16x8*)(src + kf * 16);
}

// ---- Phase 2: per (b,h): rowwise sum of exp2(Q K^T), + fused final reduce ----
// 512 blocks x 128 Q-rows (mt=4 -> 4 independent MFMA chains + 64 independent
// exp2 per ct = the ILP that hides MFMA latency). Wave wv covers frag-cts
// [wv*16, wv*16+16). K loads fully-coalesced 1KB bursts from kfrag. MFMA of
// subtile n interleaved with exp2 of subtile n-1 (separate pipes overlap).
__global__ __launch_bounds__(256) void lse_kernel(
    const bf16_t* __restrict__ qk, const bf16_t* __restrict__ kfrag,
    float* __restrict__ red, unsigned* __restrict__ cnt, float* __restrict__ out)
{
    __shared__ float rows_s[4][128];
    __shared__ float wsf[4];
    __shared__ int lastflag;
    const int t = threadIdx.x, lane = t & 63, wv = t >> 6;
    const int bid = blockIdx.x;
    const int xcd = bid & 7, idx = bid >> 3;     // idx 0..63
    const int pair = xcd * 4 + (idx >> 4);       // 0..31, 4 pairs per XCD
    const int tile = idx & 15;                   // 0..15
    const int b = pair >> 4, h = pair & 15;
    const int qr0 = tile * 128;
    const int l31 = lane & 31, g5 = lane >> 5;
    const size_t base = (size_t)b * SEQ;

    // Q fragments (B-operand): lane holds Q-row qr0+mt*32+l31, k = kf*16+g5*8
    bf16x8 qf[4][4];
#pragma unroll
    for (int mt = 0; mt < 4; ++mt) {
        const bf16_t* qp_ = qk + (base + qr0 + mt * 32 + l31) * N_TOT + h * QKD + g5 * 8;
#pragma unroll
        for (int kf = 0; kf < 4; ++kf)
            qf[mt][kf] = *(const bf16x8*)(qp_ + kf * 16);
    }

    // K fragments: coalesced; wave wv owns cts wv*16..wv*16+15 (ct step = 2048)
    const bf16_t* kfb = kfrag + ((size_t)(pair * 64 + wv * 16) * 4) * 512 + lane * 8;

    float sume[4] = {0.f, 0.f, 0.f, 0.f};

    bf16x8 kv[4];
#pragma unroll
    for (int kf = 0; kf < 4; ++kf) kv[kf] = *(const bf16x8*)(kfb + kf * 512);

#define QK_MFMA(SACC, MT) do {                                              \
    f32x16 z_ = {};                                                         \
    SACC = z_;                                                              \
    _Pragma("unroll") for (int kf_ = 0; kf_ < 4; ++kf_)                     \
        SACC = MFMA32(kv[kf_], qf[MT][kf_], SACC); } while(0)
#define EXP_ACC(SACC, MT) do {                                              \
    float e_[8];                                                            \
    _Pragma("unroll") for (int jj_ = 0; jj_ < 8; ++jj_)                     \
        e_[jj_] = __builtin_amdgcn_exp2f(SACC[2*jj_])                       \
                + __builtin_amdgcn_exp2f(SACC[2*jj_+1]);                    \
    e_[0]+=e_[1]; e_[2]+=e_[3]; e_[4]+=e_[5]; e_[6]+=e_[7];                 \
    e_[0]+=e_[2]; e_[4]+=e_[6];                                             \
    sume[MT] += e_[0] + e_[4]; } while(0)

    for (int ct = 0; ct < 16; ++ct) {
        // prefetch next ct's K-frags (clamped on last iter)
        bf16x8 kn[4];
        const bf16_t* kn_p = kfb + (size_t)(ct < 15 ? ct + 1 : 15) * 2048;
#pragma unroll
        for (int kf = 0; kf < 4; ++kf) kn[kf] = *(const bf16x8*)(kn_p + kf * 512);

        f32x16 sacc0, sacc1, sacc2, sacc3;
        // interleave: exp2(subtile n-1) hides under MFMA chain of subtile n
        QK_MFMA(sacc0, 0);
        QK_MFMA(sacc1, 1);
        EXP_ACC(sacc0, 0);
        QK_MFMA(sacc2, 2);
        EXP_ACC(sacc1, 1);
        QK_MFMA(sacc3, 3);
        EXP_ACC(sacc2, 2);
        EXP_ACC(sacc3, 3);

#pragma unroll
        for (int kf = 0; kf < 4; ++kf) kv[kf] = kn[kf];
    }
#undef QK_MFMA
#undef EXP_ACC

    // lane + g5-partner cover all 32 K-rows of each ct for the same Q-row
#pragma unroll
    for (int mt = 0; mt < 4; ++mt) {
        float v = sume[mt] + __shfl_xor(sume[mt], 32);
        if (g5 == 0) rows_s[wv][mt * 32 + l31] = v;
    }
    __syncthreads();

    float lg = 0.f;
    if (t < 128) {
        float tot = rows_s[0][t] + rows_s[1][t] + rows_s[2][t] + rows_s[3][t];
        lg = __builtin_amdgcn_logf(tot);      // v_log_f32 = log2
    }
#pragma unroll
    for (int m = 1; m < 64; m <<= 1) lg += __shfl_xor(lg, m);
    if (lane == 0) wsf[wv] = lg;              // wv0: rows 0..63, wv1: 64..127
    __syncthreads();

    if (t == 0) {
        red[bid] = wsf[0] + wsf[1];
        __threadfence();
        unsigned d = atomicAdd(cnt, 1u);
        lastflag = (d == NBLK_LSE - 1);
    }
    __syncthreads();

    if (lastflag) {                           // last block: final reduce
        __threadfence();
        float s = red[t] + red[t + 256];
#pragma unroll
        for (int m = 1; m < 64; m <<= 1) s += __shfl_xor(s, m);
        if (lane == 0) wsf[wv] = s;
        __syncthreads();
        if (t == 0)
            out[0] = -8.0f * 0.69314718055994530942f * (wsf[0] + wsf[1] + wsf[2] + wsf[3]);
    }
}

extern "C" void kernel_launch(void* const* d_in, const int* in_sizes, int n_in,
                              void* d_out, int out_size, void* d_ws, size_t ws_size,
                              hipStream_t stream)
{
    const float* hs = (const float*)d_in[0];
    const float* qp = (const float*)d_in[1];
    const float* kp = (const float*)d_in[2];
    const float* qb = (const float*)d_in[3];
    const float* kb = (const float*)d_in[4];

    // ws layout: hsb (8MB, reused as kfrag after proj) | projb (4MB) | qk (16MB)
    //            | red (2KB) | cnt (4B)
    bf16_t* hsb   = (bf16_t*)d_ws;
    bf16_t* projb = hsb + (size_t)M_TOT * EMBED;
    bf16_t* qkb   = projb + (size_t)N_TOT * EMBED;
    float*  red   = (float*)(qkb + (size_t)M_TOT * N_TOT);
    unsigned* cnt = (unsigned*)(red + NBLK_LSE);
    float*  out   = (float*)d_out;
    bf16_t* kfrag = hsb;   // hsb dead after proj; 8MB = exactly kfrag size

    hipMemsetAsync(cnt, 0, sizeof(unsigned), stream);
    cvt_kernel<<<3072, 256, 0, stream>>>(hs, qp, kp, hsb, projb);
    proj_kernel<<<512, 256, 0, stream>>>(hsb, projb, qb, kb, qkb);
    repack_kernel<<<512, 256, 0, stream>>>(qkb, kfrag);
    lse_kernel<<<NBLK_LSE, 256, 0, stream>>>(qkb, kfrag, red, cnt, out);
}